// Round 7
// baseline (331737.646 us; speedup 1.0000x reference)
//
#include <hip/hip_runtime.h>
#include <hip/hip_bf16.h>
#include <math.h>
#include <stdio.h>

#define NWG 256
#define NT  512
#define T_  128
#define L_  8
typedef unsigned short ushort_t;

struct P {
  const float *data,*r,*y_d,*wte_w,*wte_b,*wpe,*ln1_w,*ln1_b,*qkv_w,*qkv_b,
              *proj_w,*proj_b,*ln2_w,*ln2_b,*fc_w,*fc_b,*mproj_w,*mproj_b,
              *lnf_w,*lnf_b,*head_w,*head_b;
  float *out, *y, *u, *h0, *h1, *oT, *pQ, *pP, *pF, *pM;
  ushort_t *wq, *wp, *wf, *wm;      // bf16 weights (converted at launch)
  __hip_bfloat16 *Kc, *Vc;
  unsigned long long *sync;
};

__device__ __forceinline__ float bf2f(ushort_t u) {
  return __uint_as_float(((unsigned)u) << 16);
}

// fp32 -> bf16 (RNE) weight conversion, run once per launch before gptloop.
__global__ void wconv(const float* __restrict__ src, ushort_t* __restrict__ dst, int n) {
  int i = blockIdx.x * blockDim.x + threadIdx.x;
  const int stride = gridDim.x * blockDim.x;
  for (; i < n; i += stride) {
    __hip_bfloat16 b = __float2bfloat16(src[i]);
    dst[i] = *reinterpret_cast<ushort_t*>(&b);
  }
}

// Packed barrier: one u64 per group; low32 = arrival counter, high32 = generation.
// Last of 64 arrivers resets counter and bumps gen in a single atomic.
__device__ __forceinline__ void gbar(unsigned long long* sb) {
  __syncthreads();
  if (threadIdx.x == 0) {
    unsigned long long old = __hip_atomic_fetch_add(sb, 1ULL, __ATOMIC_ACQ_REL, __HIP_MEMORY_SCOPE_AGENT);
    const unsigned gen0 = (unsigned)(old >> 32);
    if ((unsigned)old == 63u) {
      __hip_atomic_fetch_add(sb, (1ULL << 32) - 64ULL, __ATOMIC_ACQ_REL, __HIP_MEMORY_SCOPE_AGENT);
    } else {
      while ((unsigned)(__hip_atomic_load(sb, __ATOMIC_RELAXED, __HIP_MEMORY_SCOPE_AGENT) >> 32) == gen0)
        __builtin_amdgcn_s_sleep(1);
    }
    (void)__hip_atomic_load(sb, __ATOMIC_ACQUIRE, __HIP_MEMORY_SCOPE_AGENT);
  }
  __syncthreads();
}

// Cross-wave LayerNorm stats from per-thread partials (thread covers row tid&15).
__device__ __forceinline__ void stat_reduce(float s, float s2, float* red1, float* red2,
                                            float* mu_s, float* rs_s) {
  const int tid = threadIdx.x;
  red1[tid] = s; red2[tid] = s2;
  __syncthreads();
  if (tid < 16) {
    float a = 0.f, b = 0.f;
    #pragma unroll 8
    for (int i = 0; i < 32; ++i) { a += red1[i * 16 + tid]; b += red2[i * 16 + tid]; }
    const float mu = a * (1.f / 512.f);
    const float var = b * (1.f / 512.f) - mu * mu;
    mu_s[tid] = mu; rs_s[tid] = rsqrtf(var + 1e-5f);
  }
  __syncthreads();
}

#define FMA_ALL(W_, A_) \
  A_[0]+=W_*a0.x; A_[1]+=W_*a0.y; A_[2]+=W_*a0.z; A_[3]+=W_*a0.w; \
  A_[4]+=W_*a1.x; A_[5]+=W_*a1.y; A_[6]+=W_*a1.z; A_[7]+=W_*a1.w; \
  A_[8]+=W_*a2.x; A_[9]+=W_*a2.y; A_[10]+=W_*a2.z; A_[11]+=W_*a2.w; \
  A_[12]+=W_*a3.x; A_[13]+=W_*a3.y; A_[14]+=W_*a3.z; A_[15]+=W_*a3.w;

// Per-wave GEMM over a KS-row k-slice (slab[KS][16] in LDS, bf16 weights).
// lane = kq(0..7)*8 + cp(0..7): cols col0+cp*2 (one dword = 2 bf16 cols),
// k subset {kq, kq+8, ...}. 3 shfl_xor rounds sum over kq; kq==0 lanes write.
template<int KS, int BAT>
__device__ __forceinline__ void gemm_bf(const ushort_t* __restrict__ Wg, int N,
                                        const float* __restrict__ slab, int kq,
                                        float* acc0, float* acc1) {
  constexpr int NI = KS / 8;
  #pragma unroll
  for (int jb = 0; jb < NI; jb += BAT) {
    unsigned w[BAT];
    #pragma unroll
    for (int u = 0; u < BAT; ++u)
      w[u] = *(const unsigned*)(Wg + (size_t)((jb + u) * 8) * N);
    #pragma unroll
    for (int u = 0; u < BAT; ++u) {
      const float* ar = slab + (kq + (jb + u) * 8) * 16;
      const float4 a0 = *(const float4*)ar,       a1 = *(const float4*)(ar + 4),
                   a2 = *(const float4*)(ar + 8), a3 = *(const float4*)(ar + 12);
      const float wx = bf2f((ushort_t)w[u]), wy = bf2f((ushort_t)(w[u] >> 16));
      FMA_ALL(wx, acc0)
      FMA_ALL(wy, acc1)
    }
  }
  #pragma unroll
  for (int m = 0; m < 16; ++m) {
    acc0[m] += __shfl_xor(acc0[m], 8);  acc1[m] += __shfl_xor(acc1[m], 8);
    acc0[m] += __shfl_xor(acc0[m], 16); acc1[m] += __shfl_xor(acc1[m], 16);
    acc0[m] += __shfl_xor(acc0[m], 32); acc1[m] += __shfl_xor(acc1[m], 32);
  }
}

#define ACC_INIT float acc0[16], acc1[16]; \
  _Pragma("unroll") for (int m_ = 0; m_ < 16; ++m_) { acc0[m_] = 0.f; acc1[m_] = 0.f; }

#define PART_STORE(dst) do { float* op_ = (dst); \
  _Pragma("unroll") for (int q4 = 0; q4 < 4; ++q4) { \
    *(float4*)(op_ + q4 * 4)      = make_float4(acc0[q4*4], acc0[q4*4+1], acc0[q4*4+2], acc0[q4*4+3]); \
    *(float4*)(op_ + 16 + q4 * 4) = make_float4(acc1[q4*4], acc1[q4*4+1], acc1[q4*4+2], acc1[q4*4+3]); } } while (0)

__global__ __launch_bounds__(NT, 1) void gptloop(P p) {
  const int bid = blockIdx.x, tid = threadIdx.x;
  const int g  = (bid & 7) >> 1;              // XCD-pair group 0..3, 16 rows each
  const int gw = (bid >> 3) * 2 + (bid & 1);  // 0..63 within group
  unsigned long long* sb = p.sync + g * 32;
  float* h0g = p.h0 + g * 8192;               // h at layer entry   [512][16]
  float* h1g = p.h1 + g * 8192;               // h after proj-resid [512][16]
  float* oTg = p.oT + g * 8192;
  float* pQg = p.pQ + (size_t)g * 98304;      // [4][1536][16]
  float* pPg = p.pP + (size_t)g * 65536;      // [8][512][16]
  float* pFg = p.pF + (size_t)g * 131072;     // [4][2048][16]
  float* pMg = p.pM + (size_t)g * 65536;      // [8][512][16]

  __shared__ float h_lds[8192];
  __shared__ float a_slab[4096];
  __shared__ float red1[512], red2[512];
  __shared__ float att_s[2][128];
  __shared__ float qv_s[2][64];
  __shared__ float inv_s[2];
  __shared__ float mu_s[16], rs_s[16], bc[4];

  const int wv = tid >> 6, lane = tid & 63;
  const int kq = lane >> 3, cp = lane & 7;

  // ---- init: y/u state + embed(st=0) -> h0 ----
  if (gw < 16) {
    const int m = gw, b = g * 16 + m;
    const float y0 = p.y_d[b * 256], y1 = p.y_d[b * 256 + 1];
    const float e0 = p.r[b * 256] - y0, e1 = p.r[b * 256 + 1] - y1;
    const float v = e0 * p.wte_w[tid] + e1 * p.wte_w[512 + tid]
                  + 191.713f * p.wte_w[1024 + tid] + 215.888f * p.wte_w[1536 + tid]
                  + p.wte_b[tid] + p.wpe[tid];
    h0g[tid * 16 + m] = v;
    if (tid < 2) {
      p.y[b * 2 + tid] = tid ? y1 : y0;
      p.u[b * 2 + tid] = tid ? 215.888f : 191.713f;
    }
  }
  gbar(sb);

  for (int st = 0; st < T_; ++st) {
    for (int l = 0; l < L_; ++l) {
      // ==== A: fold mproj(l-1) partials (l>0) into h0 + qkv GEMM -> pQ ====
      {
        float s = 0.f, s2 = 0.f;
        if (l == 0) {
          #pragma unroll
          for (int j = 0; j < 16; ++j) {
            const int e = tid + j * 512;
            const float v = h0g[e];
            h_lds[e] = v; s += v; s2 += v * v;
          }
        } else {
          const float* mb = p.mproj_b + (l - 1) * 512;
          #pragma unroll
          for (int j = 0; j < 16; ++j) {
            const int e = tid + j * 512;
            float v = h1g[e] + mb[e >> 4];
            #pragma unroll
            for (int sl = 0; sl < 8; ++sl) v += pMg[sl * 8192 + e];
            if ((e >> 7) == gw) h0g[e] = v;   // designated materialization
            h_lds[e] = v; s += v; s2 += v * v;
          }
        }
        stat_reduce(s, s2, red1, red2, mu_s, rs_s);
        if (gw < 48) {
          const int cb = gw >> 2, ks = gw & 3;
          const float* lnw = p.ln1_w + l * 512;
          const float* lnb = p.ln1_b + l * 512;
          #pragma unroll
          for (int j = 0; j < 4; ++j) {
            const int e = tid + j * 512, kl = e >> 4, rr2 = e & 15, kg = ks * 128 + kl;
            a_slab[e] = (h_lds[kg * 16 + rr2] - mu_s[rr2]) * rs_s[rr2] * lnw[kg] + lnb[kg];
          }
          __syncthreads();
          const int col = cb * 128 + wv * 16 + cp * 2;
          ACC_INIT
          gemm_bf<128, 16>(p.wq + (size_t)l * 786432 + (size_t)(ks * 128 + kq) * 1536 + col,
                           1536, a_slab, kq, acc0, acc1);
          if (kq == 0) PART_STORE(pQg + ((size_t)ks * 1536 + col) * 16);
        }
      }
      gbar(sb);

      // ==== B: attention (fold 4 qkv partials) -> oT ====
      {
        const int pp = tid >> 8, t = tid & 255;
        const int pid = gw * 2 + pp, bl = pid >> 3, hh = pid & 7;
        const int b = g * 16 + bl;
        const size_t kvb = ((size_t)(l * 64 + b) * 8 + hh) * (size_t)8192;
        if (t < 64) {
          const int qcol = hh * 64 + t, kcol = qcol + 512, vcol = qcol + 1024;
          const float qs = pQg[(size_t)qcol*16+bl] + pQg[(24576+(size_t)qcol)*16/16*16+ (size_t)0] // placeholder removed below
                         ;
          (void)qs;
          const float q4v = pQg[(size_t)qcol*16+bl] + pQg[((size_t)1536+qcol)*16+bl]
                          + pQg[((size_t)3072+qcol)*16+bl] + pQg[((size_t)4608+qcol)*16+bl]
                          + p.qkv_b[l * 1536 + qcol];
          qv_s[pp][t] = q4v * 0.125f;
          const float kv = pQg[(size_t)kcol*16+bl] + pQg[((size_t)1536+kcol)*16+bl]
                         + pQg[((size_t)3072+kcol)*16+bl] + pQg[((size_t)4608+kcol)*16+bl]
                         + p.qkv_b[l * 1536 + kcol];
          p.Kc[kvb + st * 64 + t] = __float2bfloat16(kv);
          const float vv = pQg[(size_t)vcol*16+bl] + pQg[((size_t)1536+vcol)*16+bl]
                         + pQg[((size_t)3072+vcol)*16+bl] + pQg[((size_t)4608+vcol)*16+bl]
                         + p.qkv_b[l * 1536 + vcol];
          p.Vc[kvb + st * 64 + t] = __float2bfloat16(vv);
        }
        __syncthreads();
        float s = -1e30f;
        if (t <= st && t < 128) {
          const uint4* kp = (const uint4*)((const ushort_t*)p.Kc + kvb + (size_t)t * 64);
          float sc = 0.f;
          #pragma unroll
          for (int j2 = 0; j2 < 8; ++j2) {
            const uint4 k4 = kp[j2];
            sc += qv_s[pp][j2*8+0] * bf2f((ushort_t)k4.x)
                + qv_s[pp][j2*8+1] * bf2f((ushort_t)(k4.x >> 16))
                + qv_s[pp][j2*8+2] * bf2f((ushort_t)k4.y)
                + qv_s[pp][j2*8+3] * bf2f((ushort_t)(k4.y >> 16))
                + qv_s[pp][j2*8+4] * bf2f((ushort_t)k4.z)
                + qv_s[pp][j2*8+5] * bf2f((ushort_t)(k4.z >> 16))
                + qv_s[pp][j2*8+6] * bf2f((ushort_t)k4.w)
                + qv_s[pp][j2*8+7] * bf2f((ushort_t)(k4.w >> 16));
          }
          s = sc;
        }
        red1[tid] = s; __syncthreads();
        for (int s2 = 128; s2 >= 1; s2 >>= 1) {
          if (t < s2) red1[tid] = fmaxf(red1[tid], red1[tid + s2]);
          __syncthreads();
        }
        const float mx = red1[pp * 256];
        __syncthreads();
        const float e = (t <= st && t < 128) ? expf(s - mx) : 0.f;
        if (t < 128) att_s[pp][t] = e;
        red1[tid] = e; __syncthreads();
        for (int s2 = 128; s2 >= 1; s2 >>= 1) {
          if (t < s2) red1[tid] += red1[tid + s2];
          __syncthreads();
        }
        if (t == 0) inv_s[pp] = 1.f / red1[pp * 256];
        __syncthreads();
        const int d = t & 63, tq = t >> 6;
        float o = 0.f;
        const ushort_t* vp = (const ushort_t*)p.Vc;
        for (int tt = tq; tt <= st; tt += 4)
          o += att_s[pp][tt] * bf2f(vp[kvb + (size_t)tt * 64 + d]);
        red1[tid] = o; __syncthreads();
        if (tid < 128) {
          const int p2 = tid >> 6, d2 = tid & 63;
          const int pid2 = gw * 2 + p2, bl2 = pid2 >> 3, h2 = pid2 & 7;
          const float oo = (red1[p2*256 + d2] + red1[p2*256 + 64 + d2]
                          + red1[p2*256 + 128 + d2] + red1[p2*256 + 192 + d2]) * inv_s[p2];
          oTg[(h2 * 64 + d2) * 16 + bl2] = oo;
        }
      }
      gbar(sb);

      // ==== C: proj GEMM (32 WGs = 4 cb x 8 ks, KS=64) -> pP ====
      if (gw < 32) {
        const int cb = gw >> 3, ks = gw & 7;
        #pragma unroll
        for (int j = 0; j < 2; ++j) a_slab[tid + j * 512] = oTg[ks * 1024 + tid + j * 512];
        __syncthreads();
        const int col = cb * 128 + wv * 16 + cp * 2;
        ACC_INIT
        gemm_bf<64, 8>(p.wp + (size_t)l * 262144 + (size_t)(ks * 64 + kq) * 512 + col,
                       512, a_slab, kq, acc0, acc1);
        if (kq == 0) PART_STORE(pPg + ((size_t)ks * 512 + col) * 16);
      }
      gbar(sb);

      // ==== D: fold proj partials into h1 + fc GEMM -> pF ====
      {
        float s = 0.f, s2 = 0.f;
        const float* pb = p.proj_b + l * 512;
        #pragma unroll
        for (int j = 0; j < 16; ++j) {
          const int e = tid + j * 512;
          float v = h0g[e] + pb[e >> 4];
          #pragma unroll
          for (int sl = 0; sl < 8; ++sl) v += pPg[sl * 8192 + e];
          if ((e >> 7) == gw) h1g[e] = v;
          h_lds[e] = v; s += v; s2 += v * v;
        }
        stat_reduce(s, s2, red1, red2, mu_s, rs_s);
        const int cb = gw >> 2, ks = gw & 3;
        const float* lnw = p.ln2_w + l * 512;
        const float* lnb = p.ln2_b + l * 512;
        #pragma unroll
        for (int j = 0; j < 4; ++j) {
          const int e = tid + j * 512, kl = e >> 4, rr2 = e & 15, kg = ks * 128 + kl;
          a_slab[e] = (h_lds[kg * 16 + rr2] - mu_s[rr2]) * rs_s[rr2] * lnw[kg] + lnb[kg];
        }
        __syncthreads();
        const int col = cb * 128 + wv * 16 + cp * 2;
        ACC_INIT
        gemm_bf<128, 16>(p.wf + (size_t)l * 1048576 + (size_t)(ks * 128 + kq) * 2048 + col,
                         2048, a_slab, kq, acc0, acc1);
        if (kq == 0) PART_STORE(pFg + ((size_t)ks * 2048 + col) * 16);
      }
      gbar(sb);

      // ==== E: gelu(fold 4 fc partials) + mproj GEMM (32 WGs = 4 cb x 8 ks, KS=256) -> pM ====
      if (gw < 32) {
        const int cb = gw >> 3, ks = gw & 7;
        #pragma unroll
        for (int j = 0; j < 8; ++j) {
          const int e = tid + j * 512, kl = e >> 4, rr2 = e & 15, kg = ks * 256 + kl;
          const float x = pFg[(size_t)kg*16+rr2] + pFg[((size_t)2048+kg)*16+rr2]
                        + pFg[((size_t)4096+kg)*16+rr2] + pFg[((size_t)6144+kg)*16+rr2]
                        + p.fc_b[l * 2048 + kg];
          a_slab[e] = 0.5f * x * (1.f + erff(x * 0.70710678118654752f));
        }
        __syncthreads();
        const int col = cb * 128 + wv * 16 + cp * 2;
        ACC_INIT
        gemm_bf<256, 16>(p.wm + (size_t)l * 1048576 + (size_t)(ks * 256 + kq) * 512 + col,
                         512, a_slab, kq, acc0, acc1);
        if (kq == 0) PART_STORE(pMg + ((size_t)ks * 512 + col) * 16);
      }
      gbar(sb);
    } // layers

    // ==== final: fold mproj(7) + lnf + head + ODE + out + embed(st+1) -> h0 ====
    if (gw < 16) {
      const int m = gw, b = g * 16 + m;
      const float* mb = p.mproj_b + 7 * 512;
      float v = h1g[tid * 16 + m] + mb[tid];
      #pragma unroll
      for (int sl = 0; sl < 8; ++sl) v += pMg[sl * 8192 + tid * 16 + m];
      red1[tid] = v; red2[tid] = v * v;
      __syncthreads();
      for (int s2 = 256; s2 >= 1; s2 >>= 1) {
        if (tid < s2) { red1[tid] += red1[tid + s2]; red2[tid] += red2[tid + s2]; }
        __syncthreads();
      }
      const float mu = red1[0] * (1.f / 512.f);
      const float var = red2[0] * (1.f / 512.f) - mu * mu;
      const float rs = rsqrtf(var + 1e-5f);
      __syncthreads();
      const float hf = (v - mu) * rs * p.lnf_w[tid] + p.lnf_b[tid];
      red1[tid] = hf * p.head_w[tid * 2];
      red2[tid] = hf * p.head_w[tid * 2 + 1];
      __syncthreads();
      for (int s2 = 256; s2 >= 1; s2 >>= 1) {
        if (tid < s2) { red1[tid] += red1[tid + s2]; red2[tid] += red2[tid + s2]; }
        __syncthreads();
      }
      if (tid < 2) {
        const float un = ((tid == 0) ? red1[0] : red2[0]) + p.head_b[tid];
        const float a  = p.data[b * 4 + tid];
        const float bb = p.data[b * 4 + 2 + tid];
        const float yv = p.y[b * 2 + tid];
        p.out[b * 256 + st * 2 + tid] = yv;
        const float yn = yv - a * yv + bb * un;
        p.y[b * 2 + tid] = yn;
        p.u[b * 2 + tid] = un;
        bc[tid] = yn; bc[2 + tid] = un;
      }
      __syncthreads();
      if (st < T_ - 1) {
        const float e0 = p.r[b * 256 + (st + 1) * 2]     - bc[0];
        const float e1 = p.r[b * 256 + (st + 1) * 2 + 1] - bc[1];
        const float v2 = e0 * p.wte_w[tid] + e1 * p.wte_w[512 + tid]
                       + bc[2] * p.wte_w[1024 + tid] + bc[3] * p.wte_w[1536 + tid]
                       + p.wte_b[tid] + p.wpe[(st + 1) * 512 + tid];
        h0g[tid * 16 + m] = v2;
      }
    }
    gbar(sb);
  } // steps
}

extern "C" void kernel_launch(void* const* d_in, const int* in_sizes, int n_in,
                              void* d_out, int out_size, void* d_ws, size_t ws_size,
                              hipStream_t stream) {
  P p;
  p.data  =(const float*)d_in[0];  p.r      =(const float*)d_in[1];
  p.y_d   =(const float*)d_in[2];  p.wte_w  =(const float*)d_in[3];
  p.wte_b =(const float*)d_in[4];  p.wpe    =(const float*)d_in[5];
  p.ln1_w =(const float*)d_in[6];  p.ln1_b  =(const float*)d_in[7];
  p.qkv_w =(const float*)d_in[8];  p.qkv_b  =(const float*)d_in[9];
  p.proj_w=(const float*)d_in[10]; p.proj_b =(const float*)d_in[11];
  p.ln2_w =(const float*)d_in[12]; p.ln2_b  =(const float*)d_in[13];
  p.fc_w  =(const float*)d_in[14]; p.fc_b   =(const float*)d_in[15];
  p.mproj_w=(const float*)d_in[16];p.mproj_b=(const float*)d_in[17];
  p.lnf_w =(const float*)d_in[18]; p.lnf_b  =(const float*)d_in[19];
  p.head_w=(const float*)d_in[20]; p.head_b =(const float*)d_in[21];
  p.out = (float*)d_out;

  char* w = (char*)d_ws;
  size_t off = 0;
  p.sync=(unsigned long long*)(w+off); off += 4096;
  p.y   =(float*)(w+off);          off += 512;
  p.u   =(float*)(w+off);          off += 512;
  p.h0  =(float*)(w+off);          off += (size_t)4*8192*4;
  p.h1  =(float*)(w+off);          off += (size_t)4*8192*4;
  p.oT  =(float*)(w+off);          off += (size_t)4*8192*4;
  p.pQ  =(float*)(w+off);          off += (size_t)4*98304*4;
  p.pP  =(float*)(w+off);          off += (size_t)4*65536*4;
  p.pF  =(float*)(w+off);          off += (size_t)4*131072*4;
  p.pM  =(float*)(w+off);          off += (size_t)4*65536*4;
  p.wq  =(ushort_t*)(w+off);       off += (size_t)8*512*1536*2;
  p.wp  =(ushort_t*)(w+off);       off += (size_t)8*512*512*2;
  p.wf  =(ushort_t*)(w+off);       off += (size_t)8*512*2048*2;
  p.wm  =(ushort_t*)(w+off);       off += (size_t)8*2048*512*2;
  p.Kc  =(__hip_bfloat16*)(w+off); off += (size_t)L_*64*8*T_*64*2;
  p.Vc  =(__hip_bfloat16*)(w+off); off += (size_t)L_*64*8*T_*64*2;

  fprintf(stderr, "[gptloop] ws_size=%zu need=%zu\n", ws_size, off);
  if (ws_size < off) return;

  hipMemsetAsync(d_ws, 0, 4096, stream);
  hipLaunchKernelGGL(wconv, dim3(1024), dim3(256), 0, stream, p.qkv_w,  p.wq, 8*512*1536);
  hipLaunchKernelGGL(wconv, dim3(1024), dim3(256), 0, stream, p.proj_w, p.wp, 8*512*512);
  hipLaunchKernelGGL(wconv, dim3(1024), dim3(256), 0, stream, p.fc_w,   p.wf, 8*512*2048);
  hipLaunchKernelGGL(wconv, dim3(1024), dim3(256), 0, stream, p.mproj_w,p.wm, 8*2048*512);
  hipLaunchKernelGGL(gptloop, dim3(NWG), dim3(NT), 0, stream, p);
}

// Round 8
// 103428.467 us; speedup vs baseline: 3.2074x; 3.2074x over previous
//
#include <hip/hip_runtime.h>
#include <hip/hip_bf16.h>
#include <math.h>
#include <stdio.h>

#define NWG 256
#define NT  512
#define T_  128
#define L_  8
typedef unsigned short ushort_t;

struct P {
  const float *data,*r,*y_d,*wte_w,*wte_b,*wpe,*ln1_w,*ln1_b,*qkv_w,*qkv_b,
              *proj_w,*proj_b,*ln2_w,*ln2_b,*fc_w,*fc_b,*mproj_w,*mproj_b,
              *lnf_w,*lnf_b,*head_w,*head_b;
  float *out, *y, *u, *h0, *h1, *pP, *pM;
  ushort_t *hn1, *hn2, *qT, *oT, *gT;     // bf16 activations
  ushort_t *wq, *wp, *wf, *wm;            // bf16 weights (converted at launch)
  ushort_t *Kc, *Vc;
  unsigned long long *sync;
};

__device__ __forceinline__ float bf2f(ushort_t u) {
  return __uint_as_float(((unsigned)u) << 16);
}
__device__ __forceinline__ ushort_t f2bf(float f) {
  __hip_bfloat16 b = __float2bfloat16(f);
  return *reinterpret_cast<ushort_t*>(&b);
}

// fp32 -> bf16 weight conversion (idempotent; replayed per graph launch).
__global__ void wconv(const float* __restrict__ src, ushort_t* __restrict__ dst, int n) {
  int i = blockIdx.x * blockDim.x + threadIdx.x;
  const int stride = gridDim.x * blockDim.x;
  for (; i < n; i += stride) dst[i] = f2bf(src[i]);
}

// Packed barrier: one u64 per group; low32 = arrivals, high32 = generation.
__device__ __forceinline__ void gbar(unsigned long long* sb) {
  __syncthreads();
  if (threadIdx.x == 0) {
    unsigned long long old = __hip_atomic_fetch_add(sb, 1ULL, __ATOMIC_ACQ_REL, __HIP_MEMORY_SCOPE_AGENT);
    const unsigned gen0 = (unsigned)(old >> 32);
    if ((unsigned)old == 63u) {
      __hip_atomic_fetch_add(sb, (1ULL << 32) - 64ULL, __ATOMIC_ACQ_REL, __HIP_MEMORY_SCOPE_AGENT);
    } else {
      while ((unsigned)(__hip_atomic_load(sb, __ATOMIC_RELAXED, __HIP_MEMORY_SCOPE_AGENT) >> 32) == gen0)
        __builtin_amdgcn_s_sleep(1);
    }
    (void)__hip_atomic_load(sb, __ATOMIC_ACQUIRE, __HIP_MEMORY_SCOPE_AGENT);
  }
  __syncthreads();
}

// Stage slab[KS][16] fp32 from bf16 row-major src[16][W], rows [k0, k0+KS).
// thread (m = tid>>5, q = tid&31): rows q, q+32, ... (coalesced 64B reads; 2-way LDS banks).
template<int KS>
__device__ __forceinline__ void stage_bf(const ushort_t* __restrict__ src, int W, int k0,
                                         float* slab) {
  const int tid = threadIdx.x;
  const int m = tid >> 5, q = tid & 31;
  const ushort_t* sp = src + m * W + k0;
  #pragma unroll
  for (int i = 0; i < KS / 32; ++i)
    slab[(q + i * 32) * 16 + m] = bf2f(sp[q + i * 32]);
}

#define FMA_ALL(W_, A_) \
  A_[0]+=W_*a0.x; A_[1]+=W_*a0.y; A_[2]+=W_*a0.z; A_[3]+=W_*a0.w; \
  A_[4]+=W_*a1.x; A_[5]+=W_*a1.y; A_[6]+=W_*a1.z; A_[7]+=W_*a1.w; \
  A_[8]+=W_*a2.x; A_[9]+=W_*a2.y; A_[10]+=W_*a2.z; A_[11]+=W_*a2.w; \
  A_[12]+=W_*a3.x; A_[13]+=W_*a3.y; A_[14]+=W_*a3.z; A_[15]+=W_*a3.w;

// Per-WG GEMM over KS k-rows x 32 cols x 16 rows. Wave wv: rows [wv*KS/8,...);
// lane = kq(lane>>4, 4-way k) x cp(lane&15, 16 col-pairs -> 64B W segments).
// shfl_xor(16,32) sums kq; cross-wave LDS reduce. Returns value for
// (col = tid&31, m = tid>>5). Caller must __syncthreads() between staging and call.
template<int KS, int N>
__device__ __forceinline__ float gemm_red(const ushort_t* __restrict__ Wbase,
                                          const float* __restrict__ slab, float* redw) {
  const int tid = threadIdx.x;
  const int wv = tid >> 6, lane = tid & 63;
  const int kq = lane >> 4, cp = lane & 15;
  constexpr int WR = KS / 8;
  constexpr int NJ = WR / 4;
  constexpr int BAT = NJ < 8 ? NJ : 8;
  const ushort_t* Wg = Wbase + (size_t)(wv * WR + kq) * N + cp * 2;
  const float* sb = slab + (wv * WR + kq) * 16;
  float acc0[16], acc1[16];
  #pragma unroll
  for (int m = 0; m < 16; ++m) { acc0[m] = 0.f; acc1[m] = 0.f; }
  #pragma unroll
  for (int jb = 0; jb < NJ; jb += BAT) {
    unsigned w[BAT];
    #pragma unroll
    for (int u = 0; u < BAT; ++u)
      w[u] = *(const unsigned*)(Wg + (size_t)((jb + u) * 4) * N);
    #pragma unroll
    for (int u = 0; u < BAT; ++u) {
      const float* ar = sb + (jb + u) * 64;
      const float4 a0 = *(const float4*)ar,       a1 = *(const float4*)(ar + 4),
                   a2 = *(const float4*)(ar + 8), a3 = *(const float4*)(ar + 12);
      const float wx = bf2f((ushort_t)w[u]), wy = bf2f((ushort_t)(w[u] >> 16));
      FMA_ALL(wx, acc0)
      FMA_ALL(wy, acc1)
    }
  }
  #pragma unroll
  for (int m = 0; m < 16; ++m) {
    acc0[m] += __shfl_xor(acc0[m], 16); acc1[m] += __shfl_xor(acc1[m], 16);
    acc0[m] += __shfl_xor(acc0[m], 32); acc1[m] += __shfl_xor(acc1[m], 32);
  }
  if (lane < 16) {
    float* rp = redw + wv * 528 + lane * 33;
    #pragma unroll
    for (int m = 0; m < 16; ++m) { rp[m] = acc0[m]; rp[16 + m] = acc1[m]; }
  }
  __syncthreads();
  const int col = tid & 31, m2 = tid >> 5;
  float s = 0.f;
  #pragma unroll
  for (int w2 = 0; w2 < 8; ++w2)
    s += redw[w2 * 528 + (col >> 1) * 33 + (col & 1) * 16 + m2];
  return s;
}

__global__ __launch_bounds__(NT, 1) void gptloop(P p) {
  const int bid = blockIdx.x, tid = threadIdx.x;
  const int g  = (bid & 7) >> 1;              // XCD-pair group 0..3, 16 rows each
  const int gw = (bid >> 3) * 2 + (bid & 1);  // 0..63 within group
  unsigned long long* sb = p.sync + g * 32;
  float*    h0g  = p.h0  + g * 8192;          // [16][512] fp32 residual
  float*    h1g  = p.h1  + g * 8192;
  float*    pPg  = p.pP  + (size_t)g * 32768; // [4][16][512] fp32
  float*    pMg  = p.pM  + (size_t)g * 32768;
  ushort_t* hn1g = p.hn1 + g * 8192;          // [16][512] bf16 LN1(h)
  ushort_t* hn2g = p.hn2 + g * 8192;
  ushort_t* qTg  = p.qT  + g * 8192;
  ushort_t* oTg  = p.oT  + g * 8192;
  ushort_t* gTg  = p.gT  + g * 32768;         // [16][2048] bf16 gelu(fc)

  __shared__ float slab[8192];                // [512][16] staged A
  __shared__ float redw[8 * 528];             // cross-wave GEMM reduce
  __shared__ float red1[512], red2[512];
  __shared__ float att_s[2][128];
  __shared__ float qv_s[2][64];
  __shared__ float inv_s[2];
  __shared__ float bc[4];

  // ---- init: y/u + embed(st=0) -> h0, hn1 (16 WGs, one row each) ----
  if (gw < 16) {
    const int m = gw, b = g * 16 + m, t = tid;
    const float y0 = p.y_d[b * 256], y1 = p.y_d[b * 256 + 1];
    const float e0 = p.r[b * 256] - y0, e1 = p.r[b * 256 + 1] - y1;
    const float v = e0 * p.wte_w[t] + e1 * p.wte_w[512 + t]
                  + 191.713f * p.wte_w[1024 + t] + 215.888f * p.wte_w[1536 + t]
                  + p.wte_b[t] + p.wpe[t];
    h0g[m * 512 + t] = v;
    red1[t] = v; red2[t] = v * v;
    __syncthreads();
    for (int s2 = 256; s2 >= 1; s2 >>= 1) {
      if (t < s2) { red1[t] += red1[t + s2]; red2[t] += red2[t + s2]; }
      __syncthreads();
    }
    const float mu = red1[0] * (1.f / 512.f);
    const float rs = rsqrtf(red2[0] * (1.f / 512.f) - mu * mu + 1e-5f);
    hn1g[m * 512 + t] = f2bf((v - mu) * rs * p.ln1_w[t] + p.ln1_b[t]);
    if (t < 2) {
      p.y[b * 2 + t] = t ? y1 : y0;
      p.u[b * 2 + t] = t ? 215.888f : 191.713f;
    }
  }
  gbar(sb);

  for (int st = 0; st < T_; ++st) {
    for (int l = 0; l < L_; ++l) {
      // ==== A: qkv full-K (48 WGs x 32 cols) -> qT / Kc,Vc ====
      if (gw < 48) {
        stage_bf<512>(hn1g, 512, 0, slab);
        __syncthreads();
        float v = gemm_red<512, 1536>(p.wq + (size_t)l * 786432 + gw * 32, slab, redw);
        const int col = tid & 31, m = tid >> 5;
        const int gcol = gw * 32 + col;
        v += p.qkv_b[l * 1536 + gcol];
        const int part = gcol >> 9, head = (gcol & 511) >> 6, off = gcol & 63;
        const int b = g * 16 + m;
        if (part == 0) {
          qTg[m * 512 + (gcol & 511)] = f2bf(v * 0.125f);   // fold 1/sqrt(HD)
        } else {
          ushort_t* dst = (part == 1) ? p.Kc : p.Vc;
          dst[((size_t)(l * 64 + b) * 8 + head) * 8192 + st * 64 + off] = f2bf(v);
        }
      }
      gbar(sb);

      // ==== B: attention (64 WGs x 2 (b,h) pairs) -> oT ====
      {
        const int pp = tid >> 8, t = tid & 255;
        const int pid = gw * 2 + pp, bl = pid >> 3, hh = pid & 7;
        const int b = g * 16 + bl;
        const size_t kvb = ((size_t)(l * 64 + b) * 8 + hh) * (size_t)8192;
        if (t < 64) qv_s[pp][t] = bf2f(qTg[bl * 512 + hh * 64 + t]);
        __syncthreads();
        float s = -1e30f;
        if (t <= st && t < 128) {
          const uint4* kp = (const uint4*)(p.Kc + kvb + (size_t)t * 64);
          float sc = 0.f;
          #pragma unroll
          for (int j2 = 0; j2 < 8; ++j2) {
            const uint4 k4 = kp[j2];
            sc += qv_s[pp][j2*8+0] * bf2f((ushort_t)k4.x)
                + qv_s[pp][j2*8+1] * bf2f((ushort_t)(k4.x >> 16))
                + qv_s[pp][j2*8+2] * bf2f((ushort_t)k4.y)
                + qv_s[pp][j2*8+3] * bf2f((ushort_t)(k4.y >> 16))
                + qv_s[pp][j2*8+4] * bf2f((ushort_t)k4.z)
                + qv_s[pp][j2*8+5] * bf2f((ushort_t)(k4.z >> 16))
                + qv_s[pp][j2*8+6] * bf2f((ushort_t)k4.w)
                + qv_s[pp][j2*8+7] * bf2f((ushort_t)(k4.w >> 16));
          }
          s = sc;
        }
        red1[tid] = s; __syncthreads();
        for (int s2 = 128; s2 >= 1; s2 >>= 1) {
          if (t < s2) red1[tid] = fmaxf(red1[tid], red1[tid + s2]);
          __syncthreads();
        }
        const float mx = red1[pp * 256];
        __syncthreads();
        const float e = (t <= st && t < 128) ? expf(s - mx) : 0.f;
        if (t < 128) att_s[pp][t] = e;
        red1[tid] = e; __syncthreads();
        for (int s2 = 128; s2 >= 1; s2 >>= 1) {
          if (t < s2) red1[tid] += red1[tid + s2];
          __syncthreads();
        }
        if (t == 0) inv_s[pp] = 1.f / red1[pp * 256];
        __syncthreads();
        const int d = t & 63, tq = t >> 6;
        float o = 0.f;
        for (int tt = tq; tt <= st; tt += 4)
          o += att_s[pp][tt] * bf2f(p.Vc[kvb + (size_t)tt * 64 + d]);
        red1[tid] = o; __syncthreads();
        if (tid < 128) {
          const int p2 = tid >> 6, d2 = tid & 63;
          const int pid2 = gw * 2 + p2, bl2 = pid2 >> 3, h2 = pid2 & 7;
          const float oo = (red1[p2*256 + d2] + red1[p2*256 + 64 + d2]
                          + red1[p2*256 + 128 + d2] + red1[p2*256 + 192 + d2]) * inv_s[p2];
          oTg[bl2 * 512 + h2 * 64 + d2] = f2bf(oo);
        }
      }
      gbar(sb);

      // ==== C: proj (64 WGs = 16 cb x 4 ks, K=128) -> pP[ks][m][col] ====
      {
        const int cb = gw >> 2, ks = gw & 3;
        stage_bf<128>(oTg, 512, ks * 128, slab);
        __syncthreads();
        const float v = gemm_red<128, 512>(
            p.wp + (size_t)l * 262144 + (size_t)(ks * 128) * 512 + cb * 32, slab, redw);
        const int col = tid & 31, m = tid >> 5;
        pPg[(size_t)(ks * 16 + m) * 512 + cb * 32 + col] = v;
      }
      gbar(sb);

      // ==== F1: fold proj -> h1 + LN2 -> hn2 (16 WGs, one row each) ====
      if (gw < 16) {
        const int m = gw, t = tid;
        const float v = h0g[m * 512 + t]
                      + pPg[m * 512 + t] + pPg[(16 + m) * 512 + t]
                      + pPg[(32 + m) * 512 + t] + pPg[(48 + m) * 512 + t]
                      + p.proj_b[l * 512 + t];
        h1g[m * 512 + t] = v;
        red1[t] = v; red2[t] = v * v;
        __syncthreads();
        for (int s2 = 256; s2 >= 1; s2 >>= 1) {
          if (t < s2) { red1[t] += red1[t + s2]; red2[t] += red2[t + s2]; }
          __syncthreads();
        }
        const float mu = red1[0] * (1.f / 512.f);
        const float rs = rsqrtf(red2[0] * (1.f / 512.f) - mu * mu + 1e-5f);
        hn2g[m * 512 + t] = f2bf((v - mu) * rs * p.ln2_w[l * 512 + t] + p.ln2_b[l * 512 + t]);
      }
      gbar(sb);

      // ==== D: fc full-K (64 WGs x 32 cols) + gelu -> gT ====
      {
        stage_bf<512>(hn2g, 512, 0, slab);
        __syncthreads();
        float v = gemm_red<512, 2048>(p.wf + (size_t)l * 1048576 + gw * 32, slab, redw);
        const int col = tid & 31, m = tid >> 5;
        const int gcol = gw * 32 + col;
        const float x = v + p.fc_b[l * 2048 + gcol];
        gTg[m * 2048 + gcol] = f2bf(0.5f * x * (1.f + erff(x * 0.70710678118654752f)));
      }
      gbar(sb);

      // ==== E: mproj (64 WGs = 16 cb x 4 ks, K=512) -> pM[ks][m][col] ====
      {
        const int cb = gw >> 2, ks = gw & 3;
        stage_bf<512>(gTg, 2048, ks * 512, slab);
        __syncthreads();
        const float v = gemm_red<512, 512>(
            p.wm + (size_t)l * 1048576 + (size_t)(ks * 512) * 512 + cb * 32, slab, redw);
        const int col = tid & 31, m = tid >> 5;
        pMg[(size_t)(ks * 16 + m) * 512 + cb * 32 + col] = v;
      }
      gbar(sb);

      // ==== F2: fold mproj -> h0' (+ LN1(l+1) | lnf/head/ODE/out/embed) ====
      if (gw < 16) {
        const int m = gw, t = tid, b = g * 16 + m;
        const float v = h1g[m * 512 + t]
                      + pMg[m * 512 + t] + pMg[(16 + m) * 512 + t]
                      + pMg[(32 + m) * 512 + t] + pMg[(48 + m) * 512 + t]
                      + p.mproj_b[l * 512 + t];
        red1[t] = v; red2[t] = v * v;
        __syncthreads();
        for (int s2 = 256; s2 >= 1; s2 >>= 1) {
          if (t < s2) { red1[t] += red1[t + s2]; red2[t] += red2[t + s2]; }
          __syncthreads();
        }
        const float mu = red1[0] * (1.f / 512.f);
        const float rs = rsqrtf(red2[0] * (1.f / 512.f) - mu * mu + 1e-5f);
        __syncthreads();
        if (l < L_ - 1) {
          h0g[m * 512 + t] = v;
          hn1g[m * 512 + t] = f2bf((v - mu) * rs * p.ln1_w[(l + 1) * 512 + t]
                                   + p.ln1_b[(l + 1) * 512 + t]);
        } else {
          const float hf = (v - mu) * rs * p.lnf_w[t] + p.lnf_b[t];
          red1[t] = hf * p.head_w[t * 2];
          red2[t] = hf * p.head_w[t * 2 + 1];
          __syncthreads();
          for (int s2 = 256; s2 >= 1; s2 >>= 1) {
            if (t < s2) { red1[t] += red1[t + s2]; red2[t] += red2[t + s2]; }
            __syncthreads();
          }
          if (t < 2) {
            const float un = ((t == 0) ? red1[0] : red2[0]) + p.head_b[t];
            const float a  = p.data[b * 4 + t];
            const float bb = p.data[b * 4 + 2 + t];
            const float yv = p.y[b * 2 + t];
            p.out[b * 256 + st * 2 + t] = yv;
            const float yn = yv - a * yv + bb * un;
            p.y[b * 2 + t] = yn;
            p.u[b * 2 + t] = un;
            bc[t] = yn; bc[2 + t] = un;
          }
          __syncthreads();
          if (st < T_ - 1) {
            const float e0 = p.r[b * 256 + (st + 1) * 2]     - bc[0];
            const float e1 = p.r[b * 256 + (st + 1) * 2 + 1] - bc[1];
            const float v2 = e0 * p.wte_w[t] + e1 * p.wte_w[512 + t]
                           + bc[2] * p.wte_w[1024 + t] + bc[3] * p.wte_w[1536 + t]
                           + p.wte_b[t] + p.wpe[(st + 1) * 512 + t];
            h0g[m * 512 + t] = v2;
            red1[t] = v2; red2[t] = v2 * v2;
            __syncthreads();
            for (int s2 = 256; s2 >= 1; s2 >>= 1) {
              if (t < s2) { red1[t] += red1[t + s2]; red2[t] += red2[t + s2]; }
              __syncthreads();
            }
            const float mu2 = red1[0] * (1.f / 512.f);
            const float rs2 = rsqrtf(red2[0] * (1.f / 512.f) - mu2 * mu2 + 1e-5f);
            hn1g[m * 512 + t] = f2bf((v2 - mu2) * rs2 * p.ln1_w[t] + p.ln1_b[t]);
          }
        }
      }
      gbar(sb);
    } // layers
  } // steps
}

extern "C" void kernel_launch(void* const* d_in, const int* in_sizes, int n_in,
                              void* d_out, int out_size, void* d_ws, size_t ws_size,
                              hipStream_t stream) {
  P p;
  p.data  =(const float*)d_in[0];  p.r      =(const float*)d_in[1];
  p.y_d   =(const float*)d_in[2];  p.wte_w  =(const float*)d_in[3];
  p.wte_b =(const float*)d_in[4];  p.wpe    =(const float*)d_in[5];
  p.ln1_w =(const float*)d_in[6];  p.ln1_b  =(const float*)d_in[7];
  p.qkv_w =(const float*)d_in[8];  p.qkv_b  =(const float*)d_in[9];
  p.proj_w=(const float*)d_in[10]; p.proj_b =(const float*)d_in[11];
  p.ln2_w =(const float*)d_in[12]; p.ln2_b  =(const float*)d_in[13];
  p.fc_w  =(const float*)d_in[14]; p.fc_b   =(const float*)d_in[15];
  p.mproj_w=(const float*)d_in[16];p.mproj_b=(const float*)d_in[17];
  p.lnf_w =(const float*)d_in[18]; p.lnf_b  =(const float*)d_in[19];
  p.head_w=(const float*)d_in[20]; p.head_b =(const float*)d_in[21];
  p.out = (float*)d_out;

  char* w = (char*)d_ws;
  size_t off = 0;
  p.sync=(unsigned long long*)(w+off); off += 4096;
  p.y   =(float*)(w+off);          off += 512;
  p.u   =(float*)(w+off);          off += 512;
  p.h0  =(float*)(w+off);          off += (size_t)4*8192*4;
  p.h1  =(float*)(w+off);          off += (size_t)4*8192*4;
  p.pP  =(float*)(w+off);          off += (size_t)4*32768*4;
  p.pM  =(float*)(w+off);          off += (size_t)4*32768*4;
  p.hn1 =(ushort_t*)(w+off);       off += (size_t)4*8192*2;
  p.hn2 =(ushort_t*)(w+off);       off += (size_t)4*8192*2;
  p.qT  =(ushort_t*)(w+off);       off += (size_t)4*8192*2;
  p.oT  =(ushort_t*)(w+off);       off += (size_t)4*8192*2;
  p.gT  =(ushort_t*)(w+off);       off += (size_t)4*32768*2;
  p.wq  =(ushort_t*)(w+off);       off += (size_t)8*512*1536*2;
  p.wp  =(ushort_t*)(w+off);       off += (size_t)8*512*512*2;
  p.wf  =(ushort_t*)(w+off);       off += (size_t)8*512*2048*2;
  p.wm  =(ushort_t*)(w+off);       off += (size_t)8*2048*512*2;
  p.Kc  =(ushort_t*)(w+off);       off += (size_t)L_*64*8*T_*64*2;
  p.Vc  =(ushort_t*)(w+off);       off += (size_t)L_*64*8*T_*64*2;

  fprintf(stderr, "[gptloop] ws_size=%zu need=%zu\n", ws_size, off);
  if (ws_size < off) return;

  hipMemsetAsync(d_ws, 0, 4096, stream);
  hipLaunchKernelGGL(wconv, dim3(1024), dim3(256), 0, stream, p.qkv_w,  p.wq, 8*512*1536);
  hipLaunchKernelGGL(wconv, dim3(1024), dim3(256), 0, stream, p.proj_w, p.wp, 8*512*512);
  hipLaunchKernelGGL(wconv, dim3(1024), dim3(256), 0, stream, p.fc_w,   p.wf, 8*512*2048);
  hipLaunchKernelGGL(wconv, dim3(1024), dim3(256), 0, stream, p.mproj_w,p.wm, 8*2048*512);
  hipLaunchKernelGGL(gptloop, dim3(NWG), dim3(NT), 0, stream, p);
}

// Round 9
// 102380.597 us; speedup vs baseline: 3.2402x; 1.0102x over previous
//
#include <hip/hip_runtime.h>
#include <hip/hip_bf16.h>
#include <math.h>
#include <stdio.h>

#define NWG 256
#define NT  512
#define T_  128
#define L_  8
typedef unsigned short ushort_t;

struct P {
  const float *data,*r,*y_d,*wte_w,*wte_b,*wpe,*ln1_w,*ln1_b,*qkv_w,*qkv_b,
              *proj_w,*proj_b,*ln2_w,*ln2_b,*fc_w,*fc_b,*mproj_w,*mproj_b,
              *lnf_w,*lnf_b,*head_w,*head_b;
  float *out, *y, *u, *h0, *h1, *pP, *pM;
  ushort_t *hn1, *hn2, *qT, *oT, *gT;     // bf16 activations
  ushort_t *wq, *wp, *wf, *wm;            // bf16 weights (converted at launch)
  ushort_t *Kc, *Vc;
  unsigned long long *sync;
};

__device__ __forceinline__ float bf2f(ushort_t u) {
  return __uint_as_float(((unsigned)u) << 16);
}
__device__ __forceinline__ ushort_t f2bf(float f) {
  __hip_bfloat16 b = __float2bfloat16(f);
  return *reinterpret_cast<ushort_t*>(&b);
}

// fp32 -> bf16 weight conversion (idempotent; replayed per graph launch).
__global__ void wconv(const float* __restrict__ src, ushort_t* __restrict__ dst, int n) {
  int i = blockIdx.x * blockDim.x + threadIdx.x;
  const int stride = gridDim.x * blockDim.x;
  for (; i < n; i += stride) dst[i] = f2bf(src[i]);
}

// Two-level barrier: 8 leaf counters (8 WGs each, 128B-separated lines)
// -> root(8) -> generation bump. Cuts same-line RMW serialization 64 -> 8+8.
// gs = group's 2KB sync region (u64[256]).
__device__ __forceinline__ void gbar(unsigned long long* gs, int gw) {
  __syncthreads();
  if (threadIdx.x == 0) {
    unsigned long long* leaf = gs + (gw >> 3) * 16;
    unsigned long long* root = gs + 128;
    unsigned long long* gen  = gs + 144;
    const unsigned long long g0 = __hip_atomic_load(gen, __ATOMIC_RELAXED, __HIP_MEMORY_SCOPE_AGENT);
    const unsigned long long lo = __hip_atomic_fetch_add(leaf, 1ULL, __ATOMIC_ACQ_REL, __HIP_MEMORY_SCOPE_AGENT);
    if (lo == 7ULL) {
      __hip_atomic_store(leaf, 0ULL, __ATOMIC_RELAXED, __HIP_MEMORY_SCOPE_AGENT);
      const unsigned long long ro = __hip_atomic_fetch_add(root, 1ULL, __ATOMIC_ACQ_REL, __HIP_MEMORY_SCOPE_AGENT);
      if (ro == 7ULL) {
        __hip_atomic_store(root, 0ULL, __ATOMIC_RELAXED, __HIP_MEMORY_SCOPE_AGENT);
        __hip_atomic_fetch_add(gen, 1ULL, __ATOMIC_RELEASE, __HIP_MEMORY_SCOPE_AGENT);
      }
    }
    while (__hip_atomic_load(gen, __ATOMIC_RELAXED, __HIP_MEMORY_SCOPE_AGENT) == g0)
      __builtin_amdgcn_s_sleep(1);
    (void)__hip_atomic_load(gen, __ATOMIC_ACQUIRE, __HIP_MEMORY_SCOPE_AGENT);
  }
  __syncthreads();
}

// Bank-swizzle: logical (k, m) stored at word k*16 + (m ^ swz(k)),
// swz(k) = ((k>>1)&3)<<2. Keeps float4 blocks aligned (block j at j^c4);
// staging writes go from 16-way to 4-way bank conflict.
__device__ __forceinline__ int swz4(int k) { return ((k >> 1) & 3); }

// Stage slab[KS][16] fp32 (swizzled) from bf16 row-major src[16][W], rows [k0,k0+KS).
template<int KS>
__device__ __forceinline__ void stage_bf(const ushort_t* __restrict__ src, int W, int k0,
                                         float* slab) {
  const int tid = threadIdx.x;
  const int m = tid >> 5, q = tid & 31;
  const ushort_t* sp = src + m * W + k0;
  #pragma unroll
  for (int i = 0; i < KS / 32; ++i) {
    const int k = q + i * 32;
    slab[k * 16 + (m ^ (swz4(k) << 2))] = bf2f(sp[k]);
  }
}

#define FMA_ALL(W_, A_) \
  A_[0]+=W_*a0.x; A_[1]+=W_*a0.y; A_[2]+=W_*a0.z; A_[3]+=W_*a0.w; \
  A_[4]+=W_*a1.x; A_[5]+=W_*a1.y; A_[6]+=W_*a1.z; A_[7]+=W_*a1.w; \
  A_[8]+=W_*a2.x; A_[9]+=W_*a2.y; A_[10]+=W_*a2.z; A_[11]+=W_*a2.w; \
  A_[12]+=W_*a3.x; A_[13]+=W_*a3.y; A_[14]+=W_*a3.z; A_[15]+=W_*a3.w;

// Per-WG GEMM over KS k-rows x 32 cols x 16 rows. Wave wv: rows [wv*KS/8, ...);
// lane = kq(lane>>4, 4-way k) x cp(lane&15, 16 col-pairs -> 64B W segments).
// All NJ weight loads issued up-front (single waitcnt round). shfl_xor(16,32)
// sums kq; cross-wave LDS reduce. Returns value for (col=tid&31, m=tid>>5).
template<int KS, int N>
__device__ __forceinline__ float gemm_red(const ushort_t* __restrict__ Wbase,
                                          const float* __restrict__ slab, float* redw) {
  const int tid = threadIdx.x;
  const int wv = tid >> 6, lane = tid & 63;
  const int kq = lane >> 4, cp = lane & 15;
  constexpr int WR = KS / 8;
  constexpr int NJ = WR / 4;
  constexpr int BAT = NJ < 16 ? NJ : 16;
  const int r0 = wv * WR + kq;
  const ushort_t* Wg = Wbase + (size_t)r0 * N + cp * 2;
  float acc0[16], acc1[16];
  #pragma unroll
  for (int m = 0; m < 16; ++m) { acc0[m] = 0.f; acc1[m] = 0.f; }
  #pragma unroll
  for (int jb = 0; jb < NJ; jb += BAT) {
    unsigned w[BAT];
    #pragma unroll
    for (int u = 0; u < BAT; ++u)
      w[u] = *(const unsigned*)(Wg + (size_t)((jb + u) * 4) * N);
    #pragma unroll
    for (int u = 0; u < BAT; ++u) {
      const int row = r0 + (jb + u) * 4;
      const float4* b4 = (const float4*)(slab + row * 16);
      const int c4 = swz4(row);
      const float4 a0 = b4[0 ^ c4], a1 = b4[1 ^ c4], a2 = b4[2 ^ c4], a3 = b4[3 ^ c4];
      const float wx = bf2f((ushort_t)w[u]), wy = bf2f((ushort_t)(w[u] >> 16));
      FMA_ALL(wx, acc0)
      FMA_ALL(wy, acc1)
    }
  }
  #pragma unroll
  for (int m = 0; m < 16; ++m) {
    acc0[m] += __shfl_xor(acc0[m], 16); acc1[m] += __shfl_xor(acc1[m], 16);
    acc0[m] += __shfl_xor(acc0[m], 32); acc1[m] += __shfl_xor(acc1[m], 32);
  }
  if (lane < 16) {
    float* rp = redw + wv * 528 + lane * 33;
    #pragma unroll
    for (int m = 0; m < 16; ++m) { rp[m] = acc0[m]; rp[16 + m] = acc1[m]; }
  }
  __syncthreads();
  const int col = tid & 31, m2 = tid >> 5;
  float s = 0.f;
  #pragma unroll
  for (int w2 = 0; w2 < 8; ++w2)
    s += redw[w2 * 528 + (col >> 1) * 33 + (col & 1) * 16 + m2];
  return s;
}

__global__ __launch_bounds__(NT, 1) void gptloop(P p) {
  const int bid = blockIdx.x, tid = threadIdx.x;
  const int g  = (bid & 7) >> 1;              // XCD-pair group 0..3, 16 rows each
  const int gw = (bid >> 3) * 2 + (bid & 1);  // 0..63 within group
  unsigned long long* sb = p.sync + g * 256;
  float*    h0g  = p.h0  + g * 8192;          // [16][512] fp32 residual
  float*    h1g  = p.h1  + g * 8192;
  float*    pPg  = p.pP  + (size_t)g * 32768; // [4][16][512] fp32
  float*    pMg  = p.pM  + (size_t)g * 32768;
  ushort_t* hn1g = p.hn1 + g * 8192;          // [16][512] bf16 LN1(h)
  ushort_t* hn2g = p.hn2 + g * 8192;
  ushort_t* qTg  = p.qT  + g * 8192;
  ushort_t* oTg  = p.oT  + g * 8192;
  ushort_t* gTg  = p.gT  + g * 32768;         // [16][2048] bf16 gelu(fc)

  __shared__ float slab[8192];                // [512][16] staged A (swizzled)
  __shared__ float redw[8 * 528];             // cross-wave GEMM reduce
  __shared__ float red1[512], red2[512];
  __shared__ float att_s[2][128];
  __shared__ float qv_s[2][64];
  __shared__ float inv_s[2];
  __shared__ float bc[4];

  // ---- init: y/u + embed(st=0) -> h0, hn1 (16 WGs, one row each) ----
  if (gw < 16) {
    const int m = gw, b = g * 16 + m, t = tid;
    const float y0 = p.y_d[b * 256], y1 = p.y_d[b * 256 + 1];
    const float e0 = p.r[b * 256] - y0, e1 = p.r[b * 256 + 1] - y1;
    const float v = e0 * p.wte_w[t] + e1 * p.wte_w[512 + t]
                  + 191.713f * p.wte_w[1024 + t] + 215.888f * p.wte_w[1536 + t]
                  + p.wte_b[t] + p.wpe[t];
    h0g[m * 512 + t] = v;
    red1[t] = v; red2[t] = v * v;
    __syncthreads();
    for (int s2 = 256; s2 >= 1; s2 >>= 1) {
      if (t < s2) { red1[t] += red1[t + s2]; red2[t] += red2[t + s2]; }
      __syncthreads();
    }
    const float mu = red1[0] * (1.f / 512.f);
    const float rs = rsqrtf(red2[0] * (1.f / 512.f) - mu * mu + 1e-5f);
    hn1g[m * 512 + t] = f2bf((v - mu) * rs * p.ln1_w[t] + p.ln1_b[t]);
    if (t < 2) {
      p.y[b * 2 + t] = t ? y1 : y0;
      p.u[b * 2 + t] = t ? 215.888f : 191.713f;
    }
  }
  gbar(sb, gw);

  for (int st = 0; st < T_; ++st) {
    for (int l = 0; l < L_; ++l) {
      // ==== A: qkv full-K (48 WGs x 32 cols) -> qT / Kc,Vc ====
      if (gw < 48) {
        stage_bf<512>(hn1g, 512, 0, slab);
        __syncthreads();
        float v = gemm_red<512, 1536>(p.wq + (size_t)l * 786432 + gw * 32, slab, redw);
        const int col = tid & 31, m = tid >> 5;
        const int gcol = gw * 32 + col;
        v += p.qkv_b[l * 1536 + gcol];
        const int part = gcol >> 9, head = (gcol & 511) >> 6, off = gcol & 63;
        const int b = g * 16 + m;
        if (part == 0) {
          qTg[m * 512 + (gcol & 511)] = f2bf(v * 0.125f);   // fold 1/sqrt(HD)
        } else {
          ushort_t* dst = (part == 1) ? p.Kc : p.Vc;
          dst[((size_t)(l * 64 + b) * 8 + head) * 8192 + st * 64 + off] = f2bf(v);
        }
      }
      gbar(sb, gw);

      // ==== B: attention (64 WGs x 2 (b,h) pairs) -> oT ====
      {
        const int pp = tid >> 8, t = tid & 255;
        const int pid = gw * 2 + pp, bl = pid >> 3, hh = pid & 7;
        const int b = g * 16 + bl;
        const size_t kvb = ((size_t)(l * 64 + b) * 8 + hh) * (size_t)8192;
        if (t < 64) qv_s[pp][t] = bf2f(qTg[bl * 512 + hh * 64 + t]);
        __syncthreads();
        float s = -1e30f;
        if (t <= st && t < 128) {
          const uint4* kp = (const uint4*)(p.Kc + kvb + (size_t)t * 64);
          float sc = 0.f;
          #pragma unroll
          for (int j2 = 0; j2 < 8; ++j2) {
            const uint4 k4 = kp[j2];
            sc += qv_s[pp][j2*8+0] * bf2f((ushort_t)k4.x)
                + qv_s[pp][j2*8+1] * bf2f((ushort_t)(k4.x >> 16))
                + qv_s[pp][j2*8+2] * bf2f((ushort_t)k4.y)
                + qv_s[pp][j2*8+3] * bf2f((ushort_t)(k4.y >> 16))
                + qv_s[pp][j2*8+4] * bf2f((ushort_t)k4.z)
                + qv_s[pp][j2*8+5] * bf2f((ushort_t)(k4.z >> 16))
                + qv_s[pp][j2*8+6] * bf2f((ushort_t)k4.w)
                + qv_s[pp][j2*8+7] * bf2f((ushort_t)(k4.w >> 16));
          }
          s = sc;
        }
        red1[tid] = s; __syncthreads();
        for (int s2 = 128; s2 >= 1; s2 >>= 1) {
          if (t < s2) red1[tid] = fmaxf(red1[tid], red1[tid + s2]);
          __syncthreads();
        }
        const float mx = red1[pp * 256];
        __syncthreads();
        const float e = (t <= st && t < 128) ? expf(s - mx) : 0.f;
        if (t < 128) att_s[pp][t] = e;
        red1[tid] = e; __syncthreads();
        for (int s2 = 128; s2 >= 1; s2 >>= 1) {
          if (t < s2) red1[tid] += red1[tid + s2];
          __syncthreads();
        }
        if (t == 0) inv_s[pp] = 1.f / red1[pp * 256];
        __syncthreads();
        const int d = t & 63, tq = t >> 6;
        float o = 0.f;
        for (int tt = tq; tt <= st; tt += 4)
          o += att_s[pp][tt] * bf2f(p.Vc[kvb + (size_t)tt * 64 + d]);
        red1[tid] = o; __syncthreads();
        if (tid < 128) {
          const int p2 = tid >> 6, d2 = tid & 63;
          const int pid2 = gw * 2 + p2, bl2 = pid2 >> 3, h2 = pid2 & 7;
          const float oo = (red1[p2*256 + d2] + red1[p2*256 + 64 + d2]
                          + red1[p2*256 + 128 + d2] + red1[p2*256 + 192 + d2]) * inv_s[p2];
          oTg[bl2 * 512 + h2 * 64 + d2] = f2bf(oo);
        }
      }
      gbar(sb, gw);

      // ==== C: proj (64 WGs = 16 cb x 4 ks, K=128) -> pP[ks][m][col] ====
      {
        const int cb = gw >> 2, ks = gw & 3;
        stage_bf<128>(oTg, 512, ks * 128, slab);
        __syncthreads();
        const float v = gemm_red<128, 512>(
            p.wp + (size_t)l * 262144 + (size_t)(ks * 128) * 512 + cb * 32, slab, redw);
        const int col = tid & 31, m = tid >> 5;
        pPg[(size_t)(ks * 16 + m) * 512 + cb * 32 + col] = v;
      }
      gbar(sb, gw);

      // ==== F1: fold proj -> h1 + LN2 -> hn2 (16 WGs, one row each) ====
      if (gw < 16) {
        const int m = gw, t = tid;
        const float v = h0g[m * 512 + t]
                      + pPg[m * 512 + t] + pPg[(16 + m) * 512 + t]
                      + pPg[(32 + m) * 512 + t] + pPg[(48 + m) * 512 + t]
                      + p.proj_b[l * 512 + t];
        h1g[m * 512 + t] = v;
        red1[t] = v; red2[t] = v * v;
        __syncthreads();
        for (int s2 = 256; s2 >= 1; s2 >>= 1) {
          if (t < s2) { red1[t] += red1[t + s2]; red2[t] += red2[t + s2]; }
          __syncthreads();
        }
        const float mu = red1[0] * (1.f / 512.f);
        const float rs = rsqrtf(red2[0] * (1.f / 512.f) - mu * mu + 1e-5f);
        hn2g[m * 512 + t] = f2bf((v - mu) * rs * p.ln2_w[l * 512 + t] + p.ln2_b[l * 512 + t]);
      }
      gbar(sb, gw);

      // ==== D: fc full-K (64 WGs x 32 cols) + gelu -> gT ====
      {
        stage_bf<512>(hn2g, 512, 0, slab);
        __syncthreads();
        float v = gemm_red<512, 2048>(p.wf + (size_t)l * 1048576 + gw * 32, slab, redw);
        const int col = tid & 31, m = tid >> 5;
        const int gcol = gw * 32 + col;
        const float x = v + p.fc_b[l * 2048 + gcol];
        gTg[m * 2048 + gcol] = f2bf(0.5f * x * (1.f + erff(x * 0.70710678118654752f)));
      }
      gbar(sb, gw);

      // ==== E: mproj (64 WGs = 16 cb x 4 ks, K=512) -> pM[ks][m][col] ====
      {
        const int cb = gw >> 2, ks = gw & 3;
        stage_bf<512>(gTg, 2048, ks * 512, slab);
        __syncthreads();
        const float v = gemm_red<512, 512>(
            p.wm + (size_t)l * 1048576 + (size_t)(ks * 512) * 512 + cb * 32, slab, redw);
        const int col = tid & 31, m = tid >> 5;
        pMg[(size_t)(ks * 16 + m) * 512 + cb * 32 + col] = v;
      }
      gbar(sb, gw);

      // ==== F2: fold mproj -> h0' (+ LN1(l+1) | lnf/head/ODE/out/embed) ====
      if (gw < 16) {
        const int m = gw, t = tid, b = g * 16 + m;
        const float v = h1g[m * 512 + t]
                      + pMg[m * 512 + t] + pMg[(16 + m) * 512 + t]
                      + pMg[(32 + m) * 512 + t] + pMg[(48 + m) * 512 + t]
                      + p.mproj_b[l * 512 + t];
        red1[t] = v; red2[t] = v * v;
        __syncthreads();
        for (int s2 = 256; s2 >= 1; s2 >>= 1) {
          if (t < s2) { red1[t] += red1[t + s2]; red2[t] += red2[t + s2]; }
          __syncthreads();
        }
        const float mu = red1[0] * (1.f / 512.f);
        const float rs = rsqrtf(red2[0] * (1.f / 512.f) - mu * mu + 1e-5f);
        __syncthreads();
        if (l < L_ - 1) {
          h0g[m * 512 + t] = v;
          hn1g[m * 512 + t] = f2bf((v - mu) * rs * p.ln1_w[(l + 1) * 512 + t]
                                   + p.ln1_b[(l + 1) * 512 + t]);
        } else {
          const float hf = (v - mu) * rs * p.lnf_w[t] + p.lnf_b[t];
          red1[t] = hf * p.head_w[t * 2];
          red2[t] = hf * p.head_w[t * 2 + 1];
          __syncthreads();
          for (int s2 = 256; s2 >= 1; s2 >>= 1) {
            if (t < s2) { red1[t] += red1[t + s2]; red2[t] += red2[t + s2]; }
            __syncthreads();
          }
          if (t < 2) {
            const float un = ((t == 0) ? red1[0] : red2[0]) + p.head_b[t];
            const float a  = p.data[b * 4 + t];
            const float bb = p.data[b * 4 + 2 + t];
            const float yv = p.y[b * 2 + t];
            p.out[b * 256 + st * 2 + t] = yv;
            const float yn = yv - a * yv + bb * un;
            p.y[b * 2 + t] = yn;
            p.u[b * 2 + t] = un;
            bc[t] = yn; bc[2 + t] = un;
          }
          __syncthreads();
          if (st < T_ - 1) {
            const float e0 = p.r[b * 256 + (st + 1) * 2]     - bc[0];
            const float e1 = p.r[b * 256 + (st + 1) * 2 + 1] - bc[1];
            const float v2 = e0 * p.wte_w[t] + e1 * p.wte_w[512 + t]
                           + bc[2] * p.wte_w[1024 + t] + bc[3] * p.wte_w[1536 + t]
                           + p.wte_b[t] + p.wpe[(st + 1) * 512 + t];
            h0g[m * 512 + t] = v2;
            red1[t] = v2; red2[t] = v2 * v2;
            __syncthreads();
            for (int s2 = 256; s2 >= 1; s2 >>= 1) {
              if (t < s2) { red1[t] += red1[t + s2]; red2[t] += red2[t + s2]; }
              __syncthreads();
            }
            const float mu2 = red1[0] * (1.f / 512.f);
            const float rs2 = rsqrtf(red2[0] * (1.f / 512.f) - mu2 * mu2 + 1e-5f);
            hn1g[m * 512 + t] = f2bf((v2 - mu2) * rs2 * p.ln1_w[t] + p.ln1_b[t]);
          }
        }
      }
      gbar(sb, gw);
    } // layers
  } // steps
}

extern "C" void kernel_launch(void* const* d_in, const int* in_sizes, int n_in,
                              void* d_out, int out_size, void* d_ws, size_t ws_size,
                              hipStream_t stream) {
  P p;
  p.data  =(const float*)d_in[0];  p.r      =(const float*)d_in[1];
  p.y_d   =(const float*)d_in[2];  p.wte_w  =(const float*)d_in[3];
  p.wte_b =(const float*)d_in[4];  p.wpe    =(const float*)d_in[5];
  p.ln1_w =(const float*)d_in[6];  p.ln1_b  =(const float*)d_in[7];
  p.qkv_w =(const float*)d_in[8];  p.qkv_b  =(const float*)d_in[9];
  p.proj_w=(const float*)d_in[10]; p.proj_b =(const float*)d_in[11];
  p.ln2_w =(const float*)d_in[12]; p.ln2_b  =(const float*)d_in[13];
  p.fc_w  =(const float*)d_in[14]; p.fc_b   =(const float*)d_in[15];
  p.mproj_w=(const float*)d_in[16];p.mproj_b=(const float*)d_in[17];
  p.lnf_w =(const float*)d_in[18]; p.lnf_b  =(const float*)d_in[19];
  p.head_w=(const float*)d_in[20]; p.head_b =(const float*)d_in[21];
  p.out = (float*)d_out;

  char* w = (char*)d_ws;
  size_t off = 0;
  p.sync=(unsigned long long*)(w+off); off += 8192;
  p.y   =(float*)(w+off);          off += 512;
  p.u   =(float*)(w+off);          off += 512;
  p.h0  =(float*)(w+off);          off += (size_t)4*8192*4;
  p.h1  =(float*)(w+off);          off += (size_t)4*8192*4;
  p.pP  =(float*)(w+off);          off += (size_t)4*32768*4;
  p.pM  =(float*)(w+off);          off += (size_t)4*32768*4;
  p.hn1 =(ushort_t*)(w+off);       off += (size_t)4*8192*2;
  p.hn2 =(ushort_t*)(w+off);       off += (size_t)4*8192*2;
  p.qT  =(ushort_t*)(w+off);       off += (size_t)4*8192*2;
  p.oT  =(ushort_t*)(w+off);       off += (size_t)4*8192*2;
  p.gT  =(ushort_t*)(w+off);       off += (size_t)4*32768*2;
  p.wq  =(ushort_t*)(w+off);       off += (size_t)8*512*1536*2;
  p.wp  =(ushort_t*)(w+off);       off += (size_t)8*512*512*2;
  p.wf  =(ushort_t*)(w+off);       off += (size_t)8*512*2048*2;
  p.wm  =(ushort_t*)(w+off);       off += (size_t)8*2048*512*2;
  p.Kc  =(ushort_t*)(w+off);       off += (size_t)L_*64*8*T_*64*2;
  p.Vc  =(ushort_t*)(w+off);       off += (size_t)L_*64*8*T_*64*2;

  fprintf(stderr, "[gptloop] ws_size=%zu need=%zu\n", ws_size, off);
  if (ws_size < off) return;

  hipMemsetAsync(d_ws, 0, 8192, stream);
  hipLaunchKernelGGL(wconv, dim3(1024), dim3(256), 0, stream, p.qkv_w,  p.wq, 8*512*1536);
  hipLaunchKernelGGL(wconv, dim3(1024), dim3(256), 0, stream, p.proj_w, p.wp, 8*512*512);
  hipLaunchKernelGGL(wconv, dim3(1024), dim3(256), 0, stream, p.fc_w,   p.wf, 8*512*2048);
  hipLaunchKernelGGL(wconv, dim3(1024), dim3(256), 0, stream, p.mproj_w,p.wm, 8*2048*512);
  hipLaunchKernelGGL(gptloop, dim3(NWG), dim3(NT), 0, stream, p);
}